// Round 12
// baseline (952.603 us; speedup 1.0000x reference)
//
#include <hip/hip_runtime.h>
#include <hip/hip_fp16.h>
#include <hip/hip_bf16.h>

typedef __attribute__((ext_vector_type(4))) float floatx4;
typedef _Float16 f16x8 __attribute__((ext_vector_type(8)));
typedef __attribute__((ext_vector_type(8))) short short8;

constexpr int K_TOT = 4096;
constexpr int N_TOT = 11008;
constexpr int NPACK = N_TOT / 8;        // 1376
constexpr int M_TOT = 8192;

// ---------------- pass 1a: x fp32 -> fp16 ----------------
__global__ __launch_bounds__(256)
void k_cvt_x(const float* __restrict__ X, __half* __restrict__ XH, int n8) {
  int i = blockIdx.x * 256 + threadIdx.x;
  const int stride = gridDim.x * 256;
  for (; i < n8; i += stride) {
    floatx4 a = *reinterpret_cast<const floatx4*>(X + (size_t)8 * i);
    floatx4 b = *reinterpret_cast<const floatx4*>(X + (size_t)8 * i + 4);
    uint4 v;
    v.x = __builtin_bit_cast(unsigned int, __floats2half2_rn(a.x, a.y));
    v.y = __builtin_bit_cast(unsigned int, __floats2half2_rn(a.z, a.w));
    v.z = __builtin_bit_cast(unsigned int, __floats2half2_rn(b.x, b.y));
    v.w = __builtin_bit_cast(unsigned int, __floats2half2_rn(b.z, b.w));
    *reinterpret_cast<uint4*>(XH + (size_t)8 * i) = v;
  }
}

// ---------------- pass 1b: dequant + transpose -> WT[N][K] fp16 ----------------
__global__ __launch_bounds__(256)
void k_dequant(const int* __restrict__ QW, const int* __restrict__ QZ,
               const float* __restrict__ SC, __half* __restrict__ WT) {
  __shared__ __align__(16) unsigned char Ls[128 * 256];   // [col][k] fp16, 32 KiB

  const int tid  = threadIdx.x;
  const int wblk = blockIdx.x % (N_TOT / 128);
  const int kblk = blockIdx.x / (N_TOT / 128);
  const int w0 = wblk * 16;
  const int n0 = wblk * 128;
  const int k0 = kblk * 128;
  const int g  = kblk;

  const int jw = tid & 15;
  const int kc = tid >> 4;

  const int* qp = QW + (size_t)(k0 + 8 * kc) * NPACK + w0 + jw;
  int q[8];
  #pragma unroll
  for (int j = 0; j < 8; ++j) q[j] = qp[(size_t)j * NPACK];

  const unsigned int qz = (unsigned int)QZ[(size_t)g * NPACK + w0 + jw];
  const float* sp = SC + (size_t)g * N_TOT + (w0 + jw) * 8;
  floatx4 s0 = *reinterpret_cast<const floatx4*>(sp);
  floatx4 s1 = *reinterpret_cast<const floatx4*>(sp + 4);

  unsigned int zh[4], sh[4];
  #pragma unroll
  for (int i = 0; i < 4; ++i)
    zh[i] = ((qz >> (4 * i)) & 0x000F000Fu) | 0x64006400u;
  sh[0] = __builtin_bit_cast(unsigned int, __floats2half2_rn(s0.x, s0.y));
  sh[1] = __builtin_bit_cast(unsigned int, __floats2half2_rn(s0.z, s0.w));
  sh[2] = __builtin_bit_cast(unsigned int, __floats2half2_rn(s1.x, s1.y));
  sh[3] = __builtin_bit_cast(unsigned int, __floats2half2_rn(s1.z, s1.w));

  unsigned int d[8][4];
  #pragma unroll
  for (int j = 0; j < 8; ++j)
    #pragma unroll
    for (int i = 0; i < 4; ++i) {
      unsigned int u = (((unsigned int)q[j] >> (4 * i)) & 0x000F000Fu) | 0x64006400u;
      __half2 h = __builtin_bit_cast(__half2, u);
      __half2 r = __hmul2(__hsub2(h, __builtin_bit_cast(__half2, zh[i])),
                          __builtin_bit_cast(__half2, sh[i]));
      d[j][i] = __builtin_bit_cast(unsigned int, r);
    }

  #pragma unroll
  for (int c = 0; c < 8; ++c) {
    uint4 v;
    unsigned int* vv = &v.x;
    #pragma unroll
    for (int p = 0; p < 4; ++p) {
      const unsigned int lo = (c & 1) ? (d[2 * p][c >> 1] >> 16)     : (d[2 * p][c >> 1] & 0xFFFFu);
      const unsigned int hi = (c & 1) ? (d[2 * p + 1][c >> 1] >> 16) : (d[2 * p + 1][c >> 1] & 0xFFFFu);
      vv[p] = lo | (hi << 16);
    }
    const int col  = 8 * jw + c;
    const int slot = kc ^ (col & 7);
    *reinterpret_cast<uint4*>(Ls + col * 256 + slot * 16) = v;
  }

  __syncthreads();

  const int r = tid >> 1;
  const int h = tid & 1;
  __half* gout = WT + (size_t)(n0 + r) * K_TOT + k0 + h * 64;
  #pragma unroll
  for (int u = 0; u < 8; ++u) {
    const int kcr  = 8 * h + u;
    const int slot = kcr ^ (r & 7);
    uint4 v = *reinterpret_cast<const uint4*>(Ls + r * 256 + slot * 16);
    *reinterpret_cast<uint4*>(gout + u * 8) = v;
  }
}

// ---------------- pass 2: 256x128x32, 8 waves, 2 buffers, 2 blocks/CU ----------------
constexpr int BM3 = 256, BN3 = 128, BK3 = 32;
constexpr int NBM3 = M_TOT / BM3;         // 32
constexpr int NBN3 = N_TOT / BN3;         // 86
constexpr int NKT3 = K_TOT / BK3;         // 128

#define GLOAD_LDS16(gp, lp)                                                      \
  __builtin_amdgcn_global_load_lds(                                              \
      (const __attribute__((address_space(1))) unsigned int*)(gp),               \
      (__attribute__((address_space(3))) unsigned int*)(lp), 16, 0, 0)

template<int W> __device__ __forceinline__ void waitv() {
  if constexpr (W == 3)      asm volatile("s_waitcnt vmcnt(3)" ::: "memory");
  else if constexpr (W == 2) asm volatile("s_waitcnt vmcnt(2)" ::: "memory");
  else                       asm volatile("s_waitcnt vmcnt(0)" ::: "memory");
}

// slot swizzle: uniform over the bank positions for 16-consecutive-row reads
__device__ __forceinline__ int fsw(int r) { return (r >> 1) & 3; }

__global__ __launch_bounds__(512, 4)
void k_gemm(const __half* __restrict__ XH, const __half* __restrict__ WT,
            const float* __restrict__ BI, float* __restrict__ OUT) {
  // 2 buffers: A = 2 x 16 KiB, B = 2 x 8 KiB  -> 48 KiB total -> 2 blocks/CU
  __shared__ __align__(16) unsigned char Abuf[2 * 16384];
  __shared__ __align__(16) unsigned char Bbuf[2 * 8192];

  const int tid  = threadIdx.x;
  const int lane = tid & 63;
  const int wid  = tid >> 6;        // 8 waves: 4(m) x 2(n), 64x64 out each
  const int wm   = wid >> 1;
  const int wn   = wid & 1;

  // XCD-aware bijective swizzle (grid 2752 = 8*344)
  const int cpx = gridDim.x >> 3;
  const int lg  = (blockIdx.x & 7) * cpx + (blockIdx.x >> 3);
  const int m0  = (lg / NBN3) * BM3;
  const int n0  = (lg % NBN3) * BN3;

  // ---- staging: thread -> (row r0 = tid>>2 in 0..127, 16B slot sp = tid&3) ----
  // LDS dest linear; source col pre-swizzled: physical slot sp of row r holds
  // global k-chunk (sp ^ fsw(r)).  fsw(r0+128) == fsw(r0).
  const int r0  = tid >> 2;
  const int sp  = tid & 3;
  const int col = 8 * (sp ^ fsw(r0));
  const __half* aS0 = XH + (size_t)(m0 + r0) * K_TOT + col;
  const __half* aS1 = XH + (size_t)(m0 + r0 + 128) * K_TOT + col;
  const __half* bS  = WT + (size_t)(n0 + r0) * K_TOT + col;
  const int W1024 = wid * 1024;     // wave covers rows [wid*16, wid*16+16) per instr

  auto stage = [&](int T) {
    const int ca = (T & 1) << 14;   // A buffer offset (16 KiB)
    const int cb = (T & 1) << 13;   // B buffer offset (8 KiB)
    const size_t kb = (size_t)T * BK3;
    GLOAD_LDS16(aS0 + kb, Abuf + ca + W1024);
    GLOAD_LDS16(aS1 + kb, Abuf + ca + 8192 + W1024);
    GLOAD_LDS16(bS  + kb, Bbuf + cb + W1024);
  };

  // ---- fragment read offsets (conflict-free swizzled slots) ----
  const int frow = lane & 15;
  const int ksl  = lane >> 4;       // 16B k-slot 0..3
  int aoffs[4], boffs[4];
  #pragma unroll
  for (int mf = 0; mf < 4; ++mf) {
    const int r = wm * 64 + mf * 16 + frow;      // 0..255
    aoffs[mf] = r * 64 + ((ksl ^ fsw(r)) << 4);
  }
  #pragma unroll
  for (int nf = 0; nf < 4; ++nf) {
    const int r = wn * 64 + nf * 16 + frow;      // 0..127
    boffs[nf] = r * 64 + ((ksl ^ fsw(r)) << 4);
  }

  floatx4 acc[4][4];
  #pragma unroll
  for (int i = 0; i < 4; ++i)
    #pragma unroll
    for (int j = 0; j < 4; ++j)
      acc[i][j] = (floatx4){0.f, 0.f, 0.f, 0.f};

  // prologue: stage tiles 0,1 (6 loads in flight)
  stage(0);
  stage(1);

  for (int t = 0; t < NKT3; ++t) {
    if (t == NKT3 - 1) waitv<0>();  // drain final tile
    else               waitv<3>();  // own tile-t loads landed (t+1 in flight)
    __builtin_amdgcn_s_barrier();   // tile t visible to all waves
    __builtin_amdgcn_sched_barrier(0);

    const unsigned char* Ab = Abuf + ((t & 1) << 14);
    const unsigned char* Bb = Bbuf + ((t & 1) << 13);
    f16x8 afv[4], bfv[4];
    #pragma unroll
    for (int nf = 0; nf < 4; ++nf)
      bfv[nf] = *reinterpret_cast<const f16x8*>(Bb + boffs[nf]);
    #pragma unroll
    for (int mf = 0; mf < 4; ++mf)
      afv[mf] = *reinterpret_cast<const f16x8*>(Ab + aoffs[mf]);

    __builtin_amdgcn_s_setprio(1);
    #pragma unroll
    for (int mf = 0; mf < 4; ++mf)
      #pragma unroll
      for (int nf = 0; nf < 4; ++nf)
        acc[mf][nf] = __builtin_amdgcn_mfma_f32_16x16x32_f16(
            afv[mf], bfv[nf], acc[mf][nf], 0, 0, 0);
    __builtin_amdgcn_s_setprio(0);

    __builtin_amdgcn_sched_barrier(0);
    __builtin_amdgcn_s_barrier();   // all reads of buf[t&1] consumed
    __builtin_amdgcn_sched_barrier(0);
    if (t + 2 < NKT3) stage(t + 2); // refill just-freed buffer; lands next iter+1
  }

  // ---- epilogue: bias + fp32 store (C/D: col=lane&15, row=(lane>>4)*4+j) ----
  const int ocol = lane & 15;
  const int orow = (lane >> 4) << 2;
  #pragma unroll
  for (int nf = 0; nf < 4; ++nf) {
    const int gn = n0 + wn * 64 + nf * 16 + ocol;
    const float bv = BI[gn];
    #pragma unroll
    for (int mf = 0; mf < 4; ++mf) {
      const size_t gm = (size_t)(m0 + wm * 64 + mf * 16 + orow);
      #pragma unroll
      for (int j = 0; j < 4; ++j)
        OUT[(gm + j) * (size_t)N_TOT + gn] = acc[mf][nf][j] + bv;
    }
  }
}

// ---------------- fallback: round-2 fused kernel (proven) ----------------
constexpr int NBN = N_TOT / 128;
constexpr int FLDST = 40;
__device__ __forceinline__ unsigned short f2bf(float f) {
  __hip_bfloat16 h = __float2bfloat16(f);
  return __builtin_bit_cast(unsigned short, h);
}

__global__ __launch_bounds__(256, 2)
void awq_fallback(const float* __restrict__ X, const int* __restrict__ QW,
                  const int* __restrict__ QZ, const float* __restrict__ SC,
                  const float* __restrict__ BI, float* __restrict__ OUT) {
  __shared__ __align__(16) unsigned short As[128 * FLDST];
  __shared__ __align__(16) unsigned short Bs[128 * FLDST];
  const int tid = threadIdx.x, lane = tid & 63, wid = tid >> 6;
  const int wm = wid >> 1, wn = wid & 1;
  const int cpx = gridDim.x >> 3;
  const int lg = (blockIdx.x & 7) * cpx + (blockIdx.x >> 3);
  const int m0 = (lg / NBN) * 128, n0 = (lg % NBN) * 128;
  const int a_row = tid >> 1, a_col = (tid & 1) << 4;
  const float* aptr = X + (size_t)(m0 + a_row) * K_TOT + a_col;
  const int jc = tid & 15, kp = tid >> 4, nloc = jc << 3;
  const int* qptr = QW + (size_t)(2 * kp) * NPACK + (n0 >> 3) + jc;
  const int* zptr = QZ + (n0 >> 3) + jc;
  const float* sptr = SC + n0 + nloc;
  floatx4 acc[4][4];
  #pragma unroll
  for (int i = 0; i < 4; ++i)
    #pragma unroll
    for (int j = 0; j < 4; ++j) acc[i][j] = (floatx4){0.f, 0.f, 0.f, 0.f};
  floatx4 apre[4];
  #pragma unroll
  for (int i = 0; i < 4; ++i) apre[i] = *reinterpret_cast<const floatx4*>(aptr + 4 * i);
  int qa = qptr[0], qb = qptr[NPACK];
  float sc8[8], zs8[8];
  const int frow = lane & 15, koff = (lane >> 4) << 3;
  const int arow0 = wm * 64 + frow, brow0 = wn * 64 + frow;
  for (int t = 0; t < 128; ++t) {
    if ((t & 3) == 0) {
      const int g = t >> 2;
      const int qz = zptr[(size_t)g * NPACK];
      const floatx4* sp2 = reinterpret_cast<const floatx4*>(sptr + (size_t)g * N_TOT);
      floatx4 s0 = sp2[0], s1 = sp2[1];
      #pragma unroll
      for (int i = 0; i < 4; ++i) { sc8[i] = s0[i]; sc8[4 + i] = s1[i]; }
      constexpr int SH[8] = {0, 16, 4, 20, 8, 24, 12, 28};
      #pragma unroll
      for (int c = 0; c < 8; ++c) zs8[c] = (float)((qz >> SH[c]) & 15) * sc8[c];
    }
    {
      unsigned short tmp[16];
      #pragma unroll
      for (int i = 0; i < 4; ++i)
        #pragma unroll
        for (int j = 0; j < 4; ++j) tmp[4 * i + j] = f2bf(apre[i][j]);
      short8 lo, hi;
      #pragma unroll
      for (int j = 0; j < 8; ++j) { lo[j] = (short)tmp[j]; hi[j] = (short)tmp[8 + j]; }
      *reinterpret_cast<short8*>(&As[a_row * FLDST + a_col]) = lo;
      *reinterpret_cast<short8*>(&As[a_row * FLDST + a_col + 8]) = hi;
    }
    {
      constexpr int SH[8] = {0, 16, 4, 20, 8, 24, 12, 28};
      #pragma unroll
      for (int c = 0; c < 8; ++c) {
        float wa = (float)((qa >> SH[c]) & 15) * sc8[c] - zs8[c];
        float wb = (float)((qb >> SH[c]) & 15) * sc8[c] - zs8[c];
        unsigned int pair = (unsigned int)f2bf(wa) | ((unsigned int)f2bf(wb) << 16);
        const int n = nloc + c;
        const int kk2 = (2 * kp) ^ (((n >> 3) & 3) << 3);
        *reinterpret_cast<unsigned int*>(&Bs[n * FLDST + kk2]) = pair;
      }
    }
    __syncthreads();
    if (t + 1 < 128) {
      const float* ap = aptr + (t + 1) * 32;
      #pragma unroll
      for (int i = 0; i < 4; ++i) apre[i] = *reinterpret_cast<const floatx4*>(ap + 4 * i);
      const int* qp = qptr + (size_t)(t + 1) * 32 * NPACK;
      qa = qp[0]; qb = qp[NPACK];
    }
    short8 af[4], bfv[4];
    #pragma unroll
    for (int mf = 0; mf < 4; ++mf)
      af[mf] = *reinterpret_cast<const short8*>(&As[(arow0 + mf * 16) * FLDST + koff]);
    #pragma unroll
    for (int nf = 0; nf < 4; ++nf) {
      const int n = brow0 + nf * 16;
      const int kk = koff ^ (((n >> 3) & 3) << 3);
      bfv[nf] = *reinterpret_cast<const short8*>(&Bs[n * FLDST + kk]);
    }
    #pragma unroll
    for (int mf = 0; mf < 4; ++mf)
      #pragma unroll
      for (int nf = 0; nf < 4; ++nf)
        acc[mf][nf] = __builtin_amdgcn_mfma_f32_16x16x32_bf16(af[mf], bfv[nf], acc[mf][nf], 0, 0, 0);
    __syncthreads();
  }
  const int ocol = lane & 15, orow = (lane >> 4) << 2;
  #pragma unroll
  for (int nf = 0; nf < 4; ++nf) {
    const int gn = n0 + wn * 64 + nf * 16 + ocol;
    const float bv = BI[gn];
    #pragma unroll
    for (int mf = 0; mf < 4; ++mf) {
      const size_t gm = (size_t)(m0 + wm * 64 + mf * 16 + orow);
      #pragma unroll
      for (int j = 0; j < 4; ++j)
        OUT[(gm + j) * (size_t)N_TOT + gn] = acc[mf][nf][j] + bv;
    }
  }
}

extern "C" void kernel_launch(void* const* d_in, const int* in_sizes, int n_in,
                              void* d_out, int out_size, void* d_ws, size_t ws_size,
                              hipStream_t stream) {
  const float* x    = (const float*)d_in[0];
  const int*   qw   = (const int*)d_in[1];
  const int*   qz   = (const int*)d_in[2];
  const float* sc   = (const float*)d_in[3];
  const float* bias = (const float*)d_in[4];
  float* out = (float*)d_out;

  const size_t XH_BYTES = (size_t)M_TOT * K_TOT * 2;
  const size_t WT_BYTES = (size_t)N_TOT * K_TOT * 2;
  const size_t NEED = XH_BYTES + WT_BYTES;

  if (ws_size >= NEED) {
    __half* XH = (__half*)d_ws;
    __half* WT = (__half*)((char*)d_ws + XH_BYTES);
    k_cvt_x<<<2048, 256, 0, stream>>>(x, XH, M_TOT * K_TOT / 8);
    k_dequant<<<(N_TOT / 128) * (K_TOT / 128), 256, 0, stream>>>(qw, qz, sc, WT);
    k_gemm<<<NBM3 * NBN3, 512, 0, stream>>>(XH, WT, bias, out);
  } else {
    awq_fallback<<<(M_TOT / 128) * NBN, 256, 0, stream>>>(x, qw, qz, sc, bias, out);
  }
}

// Round 13
// 845.021 us; speedup vs baseline: 1.1273x; 1.1273x over previous
//
#include <hip/hip_runtime.h>
#include <hip/hip_fp16.h>
#include <hip/hip_bf16.h>

typedef __attribute__((ext_vector_type(4))) float floatx4;
typedef _Float16 f16x8 __attribute__((ext_vector_type(8)));
typedef __attribute__((ext_vector_type(8))) short short8;

constexpr int K_TOT = 4096;
constexpr int N_TOT = 11008;
constexpr int NPACK = N_TOT / 8;        // 1376
constexpr int M_TOT = 8192;

// ---------------- pass 1a: x fp32 -> fp16 ----------------
__global__ __launch_bounds__(256)
void k_cvt_x(const float* __restrict__ X, __half* __restrict__ XH, int n8) {
  int i = blockIdx.x * 256 + threadIdx.x;
  const int stride = gridDim.x * 256;
  for (; i < n8; i += stride) {
    floatx4 a = *reinterpret_cast<const floatx4*>(X + (size_t)8 * i);
    floatx4 b = *reinterpret_cast<const floatx4*>(X + (size_t)8 * i + 4);
    uint4 v;
    v.x = __builtin_bit_cast(unsigned int, __floats2half2_rn(a.x, a.y));
    v.y = __builtin_bit_cast(unsigned int, __floats2half2_rn(a.z, a.w));
    v.z = __builtin_bit_cast(unsigned int, __floats2half2_rn(b.x, b.y));
    v.w = __builtin_bit_cast(unsigned int, __floats2half2_rn(b.z, b.w));
    *reinterpret_cast<uint4*>(XH + (size_t)8 * i) = v;
  }
}

// ---------------- pass 1b: dequant + transpose -> WT[N][K] fp16 ----------------
__global__ __launch_bounds__(256)
void k_dequant(const int* __restrict__ QW, const int* __restrict__ QZ,
               const float* __restrict__ SC, __half* __restrict__ WT) {
  __shared__ __align__(16) unsigned char Ls[128 * 256];   // [col][k] fp16, 32 KiB

  const int tid  = threadIdx.x;
  const int wblk = blockIdx.x % (N_TOT / 128);
  const int kblk = blockIdx.x / (N_TOT / 128);
  const int w0 = wblk * 16;
  const int n0 = wblk * 128;
  const int k0 = kblk * 128;
  const int g  = kblk;

  const int jw = tid & 15;
  const int kc = tid >> 4;

  const int* qp = QW + (size_t)(k0 + 8 * kc) * NPACK + w0 + jw;
  int q[8];
  #pragma unroll
  for (int j = 0; j < 8; ++j) q[j] = qp[(size_t)j * NPACK];

  const unsigned int qz = (unsigned int)QZ[(size_t)g * NPACK + w0 + jw];
  const float* sp = SC + (size_t)g * N_TOT + (w0 + jw) * 8;
  floatx4 s0 = *reinterpret_cast<const floatx4*>(sp);
  floatx4 s1 = *reinterpret_cast<const floatx4*>(sp + 4);

  unsigned int zh[4], sh[4];
  #pragma unroll
  for (int i = 0; i < 4; ++i)
    zh[i] = ((qz >> (4 * i)) & 0x000F000Fu) | 0x64006400u;
  sh[0] = __builtin_bit_cast(unsigned int, __floats2half2_rn(s0.x, s0.y));
  sh[1] = __builtin_bit_cast(unsigned int, __floats2half2_rn(s0.z, s0.w));
  sh[2] = __builtin_bit_cast(unsigned int, __floats2half2_rn(s1.x, s1.y));
  sh[3] = __builtin_bit_cast(unsigned int, __floats2half2_rn(s1.z, s1.w));

  unsigned int d[8][4];
  #pragma unroll
  for (int j = 0; j < 8; ++j)
    #pragma unroll
    for (int i = 0; i < 4; ++i) {
      unsigned int u = (((unsigned int)q[j] >> (4 * i)) & 0x000F000Fu) | 0x64006400u;
      __half2 h = __builtin_bit_cast(__half2, u);
      __half2 r = __hmul2(__hsub2(h, __builtin_bit_cast(__half2, zh[i])),
                          __builtin_bit_cast(__half2, sh[i]));
      d[j][i] = __builtin_bit_cast(unsigned int, r);
    }

  #pragma unroll
  for (int c = 0; c < 8; ++c) {
    uint4 v;
    unsigned int* vv = &v.x;
    #pragma unroll
    for (int p = 0; p < 4; ++p) {
      const unsigned int lo = (c & 1) ? (d[2 * p][c >> 1] >> 16)     : (d[2 * p][c >> 1] & 0xFFFFu);
      const unsigned int hi = (c & 1) ? (d[2 * p + 1][c >> 1] >> 16) : (d[2 * p + 1][c >> 1] & 0xFFFFu);
      vv[p] = lo | (hi << 16);
    }
    const int col  = 8 * jw + c;
    const int slot = kc ^ (col & 7);
    *reinterpret_cast<uint4*>(Ls + col * 256 + slot * 16) = v;
  }

  __syncthreads();

  const int r = tid >> 1;
  const int h = tid & 1;
  __half* gout = WT + (size_t)(n0 + r) * K_TOT + k0 + h * 64;
  #pragma unroll
  for (int u = 0; u < 8; ++u) {
    const int kcr  = 8 * h + u;
    const int slot = kcr ^ (r & 7);
    uint4 v = *reinterpret_cast<const uint4*>(Ls + r * 256 + slot * 16);
    *reinterpret_cast<uint4*>(gout + u * 8) = v;
  }
}

// ---------------- pass 2: 256x256x32, 16 waves, rotated pipeline ----------------
constexpr int NKT2 = K_TOT / 32;          // 128
constexpr int NBN2 = N_TOT / 256;         // 43

#define GLOAD_LDS16(gp, lp)                                                      \
  __builtin_amdgcn_global_load_lds(                                              \
      (const __attribute__((address_space(1))) unsigned int*)(gp),               \
      (__attribute__((address_space(3))) unsigned int*)(lp), 16, 0, 0)

template<int W> __device__ __forceinline__ void waitv() {
  if constexpr (W == 4)      asm volatile("s_waitcnt vmcnt(4)" ::: "memory");
  else if constexpr (W == 2) asm volatile("s_waitcnt vmcnt(2)" ::: "memory");
  else                       asm volatile("s_waitcnt vmcnt(0)" ::: "memory");
}

// slot swizzle: uniform over the bank positions for 16-consecutive-row reads
__device__ __forceinline__ int fsw(int r) { return (r >> 1) & 3; }

__global__ __launch_bounds__(1024, 4)
void k_gemm(const __half* __restrict__ XH, const __half* __restrict__ WT,
            const float* __restrict__ BI, float* __restrict__ OUT) {
  // 4 buffers x 16 KiB per operand = 128 KiB total
  __shared__ __align__(16) unsigned char Abuf[4 * 16384];
  __shared__ __align__(16) unsigned char Bbuf[4 * 16384];

  const int tid  = threadIdx.x;
  const int lane = tid & 63;
  const int wid  = tid >> 6;        // 16 waves: 4(m) x 4(n)
  const int wm   = wid >> 2;
  const int wn   = wid & 3;

  // XCD-aware bijective swizzle (grid 1376 = 8*172)
  const int cpx = gridDim.x >> 3;
  const int lg  = (blockIdx.x & 7) * cpx + (blockIdx.x >> 3);
  const int m0  = (lg / NBN2) * 256;
  const int n0  = (lg % NBN2) * 256;

  // ---- staging: 1 gload per operand per tile (1024 lanes x 16 B = 16 KB) ----
  const int r0  = tid >> 2;         // 0..255
  const int sp  = tid & 3;
  const int col = 8 * (sp ^ fsw(r0));
  const __half* aS = XH + (size_t)(m0 + r0) * K_TOT + col;
  const __half* bS = WT + (size_t)(n0 + r0) * K_TOT + col;
  unsigned char* aldsw = Abuf + wid * 1024;
  unsigned char* bldsw = Bbuf + wid * 1024;

  auto stage = [&](int T) {
    const int cb = (T & 3) << 14;
    const size_t kb = (size_t)T * 32;
    GLOAD_LDS16(aS + kb, aldsw + cb);
    GLOAD_LDS16(bS + kb, bldsw + cb);
  };

  // ---- fragment read offsets (conflict-free swizzled slots) ----
  const int frow = lane & 15;
  const int ksl  = lane >> 4;       // 16B k-slot 0..3
  int aoffs[4], boffs[4];
  #pragma unroll
  for (int mf = 0; mf < 4; ++mf) {
    const int r = wm * 64 + mf * 16 + frow;
    aoffs[mf] = r * 64 + ((ksl ^ fsw(r)) << 4);
  }
  #pragma unroll
  for (int nf = 0; nf < 4; ++nf) {
    const int r = wn * 64 + nf * 16 + frow;
    boffs[nf] = r * 64 + ((ksl ^ fsw(r)) << 4);
  }

  floatx4 acc[4][4];
  #pragma unroll
  for (int i = 0; i < 4; ++i)
    #pragma unroll
    for (int j = 0; j < 4; ++j)
      acc[i][j] = (floatx4){0.f, 0.f, 0.f, 0.f};

  f16x8 afv[4], bfv[4];
  auto read_frags = [&](int T) {
    const int cb = (T & 3) << 14;
    const unsigned char* Ab = Abuf + cb;
    const unsigned char* Bb = Bbuf + cb;
    #pragma unroll
    for (int nf = 0; nf < 4; ++nf)
      bfv[nf] = *reinterpret_cast<const f16x8*>(Bb + boffs[nf]);
    #pragma unroll
    for (int mf = 0; mf < 4; ++mf)
      afv[mf] = *reinterpret_cast<const f16x8*>(Ab + aoffs[mf]);
  };

  // ---- prologue: stage 0,1,2 (3-deep); read frags(0) ----
  stage(0);
  stage(1);
  stage(2);
  waitv<4>();                       // tile 0's 2 loads landed
  __builtin_amdgcn_s_barrier();     // publish tile 0
  read_frags(0);

  for (int t = 0; t < NKT2; ++t) {
    // outstanding at top: tiles t+1, t+2 (if staged) = up to 4 loads
    if (t < NKT2 - 2) waitv<2>();   // tile t+1 landed
    else              waitv<0>();   // drain tail
    __builtin_amdgcn_s_barrier();   // publish tile t+1 block-wide
    __builtin_amdgcn_sched_barrier(0);

    // MFMA(t) first: regs were read last iteration; lgkm long drained
    __builtin_amdgcn_s_setprio(1);
    #pragma unroll
    for (int mf = 0; mf < 4; ++mf)
      #pragma unroll
      for (int nf = 0; nf < 4; ++nf)
        acc[mf][nf] = __builtin_amdgcn_mfma_f32_16x16x32_f16(
            afv[mf], bfv[nf], acc[mf][nf], 0, 0, 0);
    __builtin_amdgcn_s_setprio(0);
    __builtin_amdgcn_sched_barrier(0);

    // reads for t+1 issue while this wave's MFMAs occupy the matrix pipe
    if (t + 1 < NKT2) read_frags(t + 1);
    if (t + 3 < NKT2) stage(t + 3);
  }

  // ---- epilogue: bias + fp32 store (C/D: col=lane&15, row=(lane>>4)*4+j) ----
  const int ocol = lane & 15;
  const int orow = (lane >> 4) << 2;
  #pragma unroll
  for (int nf = 0; nf < 4; ++nf) {
    const int gn = n0 + wn * 64 + nf * 16 + ocol;
    const float bv = BI[gn];
    #pragma unroll
    for (int mf = 0; mf < 4; ++mf) {
      const size_t gm = (size_t)(m0 + wm * 64 + mf * 16 + orow);
      #pragma unroll
      for (int j = 0; j < 4; ++j)
        OUT[(gm + j) * (size_t)N_TOT + gn] = acc[mf][nf][j] + bv;
    }
  }
}

// ---------------- fallback: round-2 fused kernel (proven) ----------------
constexpr int NBN = N_TOT / 128;
constexpr int FLDST = 40;
__device__ __forceinline__ unsigned short f2bf(float f) {
  __hip_bfloat16 h = __float2bfloat16(f);
  return __builtin_bit_cast(unsigned short, h);
}

__global__ __launch_bounds__(256, 2)
void awq_fallback(const float* __restrict__ X, const int* __restrict__ QW,
                  const int* __restrict__ QZ, const float* __restrict__ SC,
                  const float* __restrict__ BI, float* __restrict__ OUT) {
  __shared__ __align__(16) unsigned short As[128 * FLDST];
  __shared__ __align__(16) unsigned short Bs[128 * FLDST];
  const int tid = threadIdx.x, lane = tid & 63, wid = tid >> 6;
  const int wm = wid >> 1, wn = wid & 1;
  const int cpx = gridDim.x >> 3;
  const int lg = (blockIdx.x & 7) * cpx + (blockIdx.x >> 3);
  const int m0 = (lg / NBN) * 128, n0 = (lg % NBN) * 128;
  const int a_row = tid >> 1, a_col = (tid & 1) << 4;
  const float* aptr = X + (size_t)(m0 + a_row) * K_TOT + a_col;
  const int jc = tid & 15, kp = tid >> 4, nloc = jc << 3;
  const int* qptr = QW + (size_t)(2 * kp) * NPACK + (n0 >> 3) + jc;
  const int* zptr = QZ + (n0 >> 3) + jc;
  const float* sptr = SC + n0 + nloc;
  floatx4 acc[4][4];
  #pragma unroll
  for (int i = 0; i < 4; ++i)
    #pragma unroll
    for (int j = 0; j < 4; ++j) acc[i][j] = (floatx4){0.f, 0.f, 0.f, 0.f};
  floatx4 apre[4];
  #pragma unroll
  for (int i = 0; i < 4; ++i) apre[i] = *reinterpret_cast<const floatx4*>(aptr + 4 * i);
  int qa = qptr[0], qb = qptr[NPACK];
  float sc8[8], zs8[8];
  const int frow = lane & 15, koff = (lane >> 4) << 3;
  const int arow0 = wm * 64 + frow, brow0 = wn * 64 + frow;
  for (int t = 0; t < 128; ++t) {
    if ((t & 3) == 0) {
      const int g = t >> 2;
      const int qz = zptr[(size_t)g * NPACK];
      const floatx4* sp2 = reinterpret_cast<const floatx4*>(sptr + (size_t)g * N_TOT);
      floatx4 s0 = sp2[0], s1 = sp2[1];
      #pragma unroll
      for (int i = 0; i < 4; ++i) { sc8[i] = s0[i]; sc8[4 + i] = s1[i]; }
      constexpr int SH[8] = {0, 16, 4, 20, 8, 24, 12, 28};
      #pragma unroll
      for (int c = 0; c < 8; ++c) zs8[c] = (float)((qz >> SH[c]) & 15) * sc8[c];
    }
    {
      unsigned short tmp[16];
      #pragma unroll
      for (int i = 0; i < 4; ++i)
        #pragma unroll
        for (int j = 0; j < 4; ++j) tmp[4 * i + j] = f2bf(apre[i][j]);
      short8 lo, hi;
      #pragma unroll
      for (int j = 0; j < 8; ++j) { lo[j] = (short)tmp[j]; hi[j] = (short)tmp[8 + j]; }
      *reinterpret_cast<short8*>(&As[a_row * FLDST + a_col]) = lo;
      *reinterpret_cast<short8*>(&As[a_row * FLDST + a_col + 8]) = hi;
    }
    {
      constexpr int SH[8] = {0, 16, 4, 20, 8, 24, 12, 28};
      #pragma unroll
      for (int c = 0; c < 8; ++c) {
        float wa = (float)((qa >> SH[c]) & 15) * sc8[c] - zs8[c];
        float wb = (float)((qb >> SH[c]) & 15) * sc8[c] - zs8[c];
        unsigned int pair = (unsigned int)f2bf(wa) | ((unsigned int)f2bf(wb) << 16);
        const int n = nloc + c;
        const int kk2 = (2 * kp) ^ (((n >> 3) & 3) << 3);
        *reinterpret_cast<unsigned int*>(&Bs[n * FLDST + kk2]) = pair;
      }
    }
    __syncthreads();
    if (t + 1 < 128) {
      const float* ap = aptr + (t + 1) * 32;
      #pragma unroll
      for (int i = 0; i < 4; ++i) apre[i] = *reinterpret_cast<const floatx4*>(ap + 4 * i);
      const int* qp = qptr + (size_t)(t + 1) * 32 * NPACK;
      qa = qp[0]; qb = qp[NPACK];
    }
    short8 af[4], bfv2[4];
    #pragma unroll
    for (int mf = 0; mf < 4; ++mf)
      af[mf] = *reinterpret_cast<const short8*>(&As[(arow0 + mf * 16) * FLDST + koff]);
    #pragma unroll
    for (int nf = 0; nf < 4; ++nf) {
      const int n = brow0 + nf * 16;
      const int kk = koff ^ (((n >> 3) & 3) << 3);
      bfv2[nf] = *reinterpret_cast<const short8*>(&Bs[n * FLDST + kk]);
    }
    #pragma unroll
    for (int mf = 0; mf < 4; ++mf)
      #pragma unroll
      for (int nf = 0; nf < 4; ++nf)
        acc[mf][nf] = __builtin_amdgcn_mfma_f32_16x16x32_bf16(af[mf], bfv2[nf], acc[mf][nf], 0, 0, 0);
    __syncthreads();
  }
  const int ocol = lane & 15, orow = (lane >> 4) << 2;
  #pragma unroll
  for (int nf = 0; nf < 4; ++nf) {
    const int gn = n0 + wn * 64 + nf * 16 + ocol;
    const float bv = BI[gn];
    #pragma unroll
    for (int mf = 0; mf < 4; ++mf) {
      const size_t gm = (size_t)(m0 + wm * 64 + mf * 16 + orow);
      #pragma unroll
      for (int j = 0; j < 4; ++j)
        OUT[(gm + j) * (size_t)N_TOT + gn] = acc[mf][nf][j] + bv;
    }
  }
}

extern "C" void kernel_launch(void* const* d_in, const int* in_sizes, int n_in,
                              void* d_out, int out_size, void* d_ws, size_t ws_size,
                              hipStream_t stream) {
  const float* x    = (const float*)d_in[0];
  const int*   qw   = (const int*)d_in[1];
  const int*   qz   = (const int*)d_in[2];
  const float* sc   = (const float*)d_in[3];
  const float* bias = (const float*)d_in[4];
  float* out = (float*)d_out;

  const size_t XH_BYTES = (size_t)M_TOT * K_TOT * 2;
  const size_t WT_BYTES = (size_t)N_TOT * K_TOT * 2;
  const size_t NEED = XH_BYTES + WT_BYTES;

  if (ws_size >= NEED) {
    __half* XH = (__half*)d_ws;
    __half* WT = (__half*)((char*)d_ws + XH_BYTES);
    k_cvt_x<<<2048, 256, 0, stream>>>(x, XH, M_TOT * K_TOT / 8);
    k_dequant<<<(N_TOT / 128) * (K_TOT / 128), 256, 0, stream>>>(qw, qz, sc, WT);
    k_gemm<<<(M_TOT / 256) * NBN2, 1024, 0, stream>>>(XH, WT, bias, out);
  } else {
    awq_fallback<<<(M_TOT / 128) * NBN, 256, 0, stream>>>(x, qw, qz, sc, bias, out);
  }
}

// Round 14
// 813.976 us; speedup vs baseline: 1.1703x; 1.0381x over previous
//
#include <hip/hip_runtime.h>
#include <hip/hip_fp16.h>
#include <hip/hip_bf16.h>

typedef __attribute__((ext_vector_type(4))) float floatx4;
typedef _Float16 f16x8 __attribute__((ext_vector_type(8)));
typedef __attribute__((ext_vector_type(8))) short short8;

constexpr int K_TOT = 4096;
constexpr int N_TOT = 11008;
constexpr int NPACK = N_TOT / 8;        // 1376
constexpr int M_TOT = 8192;

// ---------------- pass 1a: x fp32 -> fp16 ----------------
__global__ __launch_bounds__(256)
void k_cvt_x(const float* __restrict__ X, __half* __restrict__ XH, int n8) {
  int i = blockIdx.x * 256 + threadIdx.x;
  const int stride = gridDim.x * 256;
  for (; i < n8; i += stride) {
    floatx4 a = *reinterpret_cast<const floatx4*>(X + (size_t)8 * i);
    floatx4 b = *reinterpret_cast<const floatx4*>(X + (size_t)8 * i + 4);
    uint4 v;
    v.x = __builtin_bit_cast(unsigned int, __floats2half2_rn(a.x, a.y));
    v.y = __builtin_bit_cast(unsigned int, __floats2half2_rn(a.z, a.w));
    v.z = __builtin_bit_cast(unsigned int, __floats2half2_rn(b.x, b.y));
    v.w = __builtin_bit_cast(unsigned int, __floats2half2_rn(b.z, b.w));
    *reinterpret_cast<uint4*>(XH + (size_t)8 * i) = v;
  }
}

// ---------------- pass 1b: dequant + transpose -> WT[N][K] fp16 ----------------
__global__ __launch_bounds__(256)
void k_dequant(const int* __restrict__ QW, const int* __restrict__ QZ,
               const float* __restrict__ SC, __half* __restrict__ WT) {
  __shared__ __align__(16) unsigned char Ls[128 * 256];   // [col][k] fp16, 32 KiB

  const int tid  = threadIdx.x;
  const int wblk = blockIdx.x % (N_TOT / 128);
  const int kblk = blockIdx.x / (N_TOT / 128);
  const int w0 = wblk * 16;
  const int n0 = wblk * 128;
  const int k0 = kblk * 128;
  const int g  = kblk;

  const int jw = tid & 15;
  const int kc = tid >> 4;

  const int* qp = QW + (size_t)(k0 + 8 * kc) * NPACK + w0 + jw;
  int q[8];
  #pragma unroll
  for (int j = 0; j < 8; ++j) q[j] = qp[(size_t)j * NPACK];

  const unsigned int qz = (unsigned int)QZ[(size_t)g * NPACK + w0 + jw];
  const float* sp = SC + (size_t)g * N_TOT + (w0 + jw) * 8;
  floatx4 s0 = *reinterpret_cast<const floatx4*>(sp);
  floatx4 s1 = *reinterpret_cast<const floatx4*>(sp + 4);

  unsigned int zh[4], sh[4];
  #pragma unroll
  for (int i = 0; i < 4; ++i)
    zh[i] = ((qz >> (4 * i)) & 0x000F000Fu) | 0x64006400u;
  sh[0] = __builtin_bit_cast(unsigned int, __floats2half2_rn(s0.x, s0.y));
  sh[1] = __builtin_bit_cast(unsigned int, __floats2half2_rn(s0.z, s0.w));
  sh[2] = __builtin_bit_cast(unsigned int, __floats2half2_rn(s1.x, s1.y));
  sh[3] = __builtin_bit_cast(unsigned int, __floats2half2_rn(s1.z, s1.w));

  unsigned int d[8][4];
  #pragma unroll
  for (int j = 0; j < 8; ++j)
    #pragma unroll
    for (int i = 0; i < 4; ++i) {
      unsigned int u = (((unsigned int)q[j] >> (4 * i)) & 0x000F000Fu) | 0x64006400u;
      __half2 h = __builtin_bit_cast(__half2, u);
      __half2 r = __hmul2(__hsub2(h, __builtin_bit_cast(__half2, zh[i])),
                          __builtin_bit_cast(__half2, sh[i]));
      d[j][i] = __builtin_bit_cast(unsigned int, r);
    }

  #pragma unroll
  for (int c = 0; c < 8; ++c) {
    uint4 v;
    unsigned int* vv = &v.x;
    #pragma unroll
    for (int p = 0; p < 4; ++p) {
      const unsigned int lo = (c & 1) ? (d[2 * p][c >> 1] >> 16)     : (d[2 * p][c >> 1] & 0xFFFFu);
      const unsigned int hi = (c & 1) ? (d[2 * p + 1][c >> 1] >> 16) : (d[2 * p + 1][c >> 1] & 0xFFFFu);
      vv[p] = lo | (hi << 16);
    }
    const int col  = 8 * jw + c;
    const int slot = kc ^ (col & 7);
    *reinterpret_cast<uint4*>(Ls + col * 256 + slot * 16) = v;
  }

  __syncthreads();

  const int r = tid >> 1;
  const int h = tid & 1;
  __half* gout = WT + (size_t)(n0 + r) * K_TOT + k0 + h * 64;
  #pragma unroll
  for (int u = 0; u < 8; ++u) {
    const int kcr  = 8 * h + u;
    const int slot = kcr ^ (r & 7);
    uint4 v = *reinterpret_cast<const uint4*>(Ls + r * 256 + slot * 16);
    *reinterpret_cast<uint4*>(gout + u * 8) = v;
  }
}

// ---------------- pass 2: 256x256x32, 16 waves, 4-buffer single-barrier ----------------
constexpr int NKT2 = K_TOT / 32;          // 128
constexpr int NBN2 = N_TOT / 256;         // 43

#define GLOAD_LDS16(gp, lp)                                                      \
  __builtin_amdgcn_global_load_lds(                                              \
      (const __attribute__((address_space(1))) unsigned int*)(gp),               \
      (__attribute__((address_space(3))) unsigned int*)(lp), 16, 0, 0)

template<int W> __device__ __forceinline__ void waitv() {
  if constexpr (W == 2) asm volatile("s_waitcnt vmcnt(2)" ::: "memory");
  else                  asm volatile("s_waitcnt vmcnt(0)" ::: "memory");
}

// slot swizzle: uniform over the bank positions for 16-consecutive-row reads
__device__ __forceinline__ int fsw(int r) { return (r >> 1) & 3; }

__global__ __launch_bounds__(1024, 4)
void k_gemm(const __half* __restrict__ XH, const __half* __restrict__ WT,
            const float* __restrict__ BI, float* __restrict__ OUT) {
  // 4 buffers x 16 KiB per operand = 128 KiB total
  __shared__ __align__(16) unsigned char Abuf[4 * 16384];
  __shared__ __align__(16) unsigned char Bbuf[4 * 16384];

  const int tid  = threadIdx.x;
  const int lane = tid & 63;
  const int wid  = tid >> 6;        // 16 waves: 4(m) x 4(n)
  const int wm   = wid >> 2;
  const int wn   = wid & 3;

  // XCD-aware bijective swizzle (grid 1376 = 8*172)
  const int cpx = gridDim.x >> 3;
  const int lg  = (blockIdx.x & 7) * cpx + (blockIdx.x >> 3);
  const int m0  = (lg / NBN2) * 256;
  const int n0  = (lg % NBN2) * 256;

  // ---- staging: 1 gload per operand per tile (1024 lanes x 16 B = 16 KB) ----
  // LDS dest linear; source col pre-swizzled: physical slot sp of row r holds
  // global k-chunk (sp ^ fsw(r)).
  const int r0  = tid >> 2;         // 0..255
  const int sp  = tid & 3;
  const int col = 8 * (sp ^ fsw(r0));
  const __half* aS = XH + (size_t)(m0 + r0) * K_TOT + col;
  const __half* bS = WT + (size_t)(n0 + r0) * K_TOT + col;
  unsigned char* aldsw = Abuf + wid * 1024;   // wave covers rows [wid*16, wid*16+16)
  unsigned char* bldsw = Bbuf + wid * 1024;

  auto stage = [&](int T) {
    const int cb = (T & 3) << 14;
    const size_t kb = (size_t)T * 32;
    GLOAD_LDS16(aS + kb, aldsw + cb);
    GLOAD_LDS16(bS + kb, bldsw + cb);
  };

  // ---- fragment read offsets (conflict-free swizzled slots) ----
  const int frow = lane & 15;
  const int ksl  = lane >> 4;       // 16B k-slot 0..3
  int aoffs[4], boffs[4];
  #pragma unroll
  for (int mf = 0; mf < 4; ++mf) {
    const int r = wm * 64 + mf * 16 + frow;
    aoffs[mf] = r * 64 + ((ksl ^ fsw(r)) << 4);
  }
  #pragma unroll
  for (int nf = 0; nf < 4; ++nf) {
    const int r = wn * 64 + nf * 16 + frow;
    boffs[nf] = r * 64 + ((ksl ^ fsw(r)) << 4);
  }

  floatx4 acc[4][4];
  #pragma unroll
  for (int i = 0; i < 4; ++i)
    #pragma unroll
    for (int j = 0; j < 4; ++j)
      acc[i][j] = (floatx4){0.f, 0.f, 0.f, 0.f};

  // prologue: stage tiles 0,1 (2-deep, 4 loads in flight)
  stage(0);
  stage(1);

  auto body = [&](int T, bool do_stage) {
    __builtin_amdgcn_s_barrier();                 // tile T visible to all waves
    __builtin_amdgcn_sched_barrier(0);            // pin reads below barrier
    const int cb = (T & 3) << 14;
    const unsigned char* Ab = Abuf + cb;
    const unsigned char* Bb = Bbuf + cb;
    f16x8 bfv[4], afv[4];
    #pragma unroll
    for (int nf = 0; nf < 4; ++nf)
      bfv[nf] = *reinterpret_cast<const f16x8*>(Bb + boffs[nf]);
    #pragma unroll
    for (int mf = 0; mf < 4; ++mf)
      afv[mf] = *reinterpret_cast<const f16x8*>(Ab + aoffs[mf]);
    if (do_stage) stage(T + 2);                   // issue-only; lands 2 iters out
    __builtin_amdgcn_s_setprio(1);
    #pragma unroll
    for (int mf = 0; mf < 4; ++mf)
      #pragma unroll
      for (int nf = 0; nf < 4; ++nf)
        acc[mf][nf] = __builtin_amdgcn_mfma_f32_16x16x32_f16(
            afv[mf], bfv[nf], acc[mf][nf], 0, 0, 0);
    __builtin_amdgcn_s_setprio(0);
  };

  for (int t = 0; t < NKT2 - 1; ++t) {
    waitv<2>();                 // own tile-t loads landed (t+1 may stay in flight)
    body(t, t + 2 < NKT2);
  }
  waitv<0>();
  body(NKT2 - 1, false);

  // ---- epilogue: bias + fp32 store (C/D: col=lane&15, row=(lane>>4)*4+j) ----
  const int ocol = lane & 15;
  const int orow = (lane >> 4) << 2;
  #pragma unroll
  for (int nf = 0; nf < 4; ++nf) {
    const int gn = n0 + wn * 64 + nf * 16 + ocol;
    const float bv = BI[gn];
    #pragma unroll
    for (int mf = 0; mf < 4; ++mf) {
      const size_t gm = (size_t)(m0 + wm * 64 + mf * 16 + orow);
      #pragma unroll
      for (int j = 0; j < 4; ++j)
        OUT[(gm + j) * (size_t)N_TOT + gn] = acc[mf][nf][j] + bv;
    }
  }
}

// ---------------- fallback: round-2 fused kernel (proven) ----------------
constexpr int NBN = N_TOT / 128;
constexpr int FLDST = 40;
__device__ __forceinline__ unsigned short f2bf(float f) {
  __hip_bfloat16 h = __float2bfloat16(f);
  return __builtin_bit_cast(unsigned short, h);
}

__global__ __launch_bounds__(256, 2)
void awq_fallback(const float* __restrict__ X, const int* __restrict__ QW,
                  const int* __restrict__ QZ, const float* __restrict__ SC,
                  const float* __restrict__ BI, float* __restrict__ OUT) {
  __shared__ __align__(16) unsigned short As[128 * FLDST];
  __shared__ __align__(16) unsigned short Bs[128 * FLDST];
  const int tid = threadIdx.x, lane = tid & 63, wid = tid >> 6;
  const int wm = wid >> 1, wn = wid & 1;
  const int cpx = gridDim.x >> 3;
  const int lg = (blockIdx.x & 7) * cpx + (blockIdx.x >> 3);
  const int m0 = (lg / NBN) * 128, n0 = (lg % NBN) * 128;
  const int a_row = tid >> 1, a_col = (tid & 1) << 4;
  const float* aptr = X + (size_t)(m0 + a_row) * K_TOT + a_col;
  const int jc = tid & 15, kp = tid >> 4, nloc = jc << 3;
  const int* qptr = QW + (size_t)(2 * kp) * NPACK + (n0 >> 3) + jc;
  const int* zptr = QZ + (n0 >> 3) + jc;
  const float* sptr = SC + n0 + nloc;
  floatx4 acc[4][4];
  #pragma unroll
  for (int i = 0; i < 4; ++i)
    #pragma unroll
    for (int j = 0; j < 4; ++j) acc[i][j] = (floatx4){0.f, 0.f, 0.f, 0.f};
  floatx4 apre[4];
  #pragma unroll
  for (int i = 0; i < 4; ++i) apre[i] = *reinterpret_cast<const floatx4*>(aptr + 4 * i);
  int qa = qptr[0], qb = qptr[NPACK];
  float sc8[8], zs8[8];
  const int frow = lane & 15, koff = (lane >> 4) << 3;
  const int arow0 = wm * 64 + frow, brow0 = wn * 64 + frow;
  for (int t = 0; t < 128; ++t) {
    if ((t & 3) == 0) {
      const int g = t >> 2;
      const int qz = zptr[(size_t)g * NPACK];
      const floatx4* sp2 = reinterpret_cast<const floatx4*>(sptr + (size_t)g * N_TOT);
      floatx4 s0 = sp2[0], s1 = sp2[1];
      #pragma unroll
      for (int i = 0; i < 4; ++i) { sc8[i] = s0[i]; sc8[4 + i] = s1[i]; }
      constexpr int SH[8] = {0, 16, 4, 20, 8, 24, 12, 28};
      #pragma unroll
      for (int c = 0; c < 8; ++c) zs8[c] = (float)((qz >> SH[c]) & 15) * sc8[c];
    }
    {
      unsigned short tmp[16];
      #pragma unroll
      for (int i = 0; i < 4; ++i)
        #pragma unroll
        for (int j = 0; j < 4; ++j) tmp[4 * i + j] = f2bf(apre[i][j]);
      short8 lo, hi;
      #pragma unroll
      for (int j = 0; j < 8; ++j) { lo[j] = (short)tmp[j]; hi[j] = (short)tmp[8 + j]; }
      *reinterpret_cast<short8*>(&As[a_row * FLDST + a_col]) = lo;
      *reinterpret_cast<short8*>(&As[a_row * FLDST + a_col + 8]) = hi;
    }
    {
      constexpr int SH[8] = {0, 16, 4, 20, 8, 24, 12, 28};
      #pragma unroll
      for (int c = 0; c < 8; ++c) {
        float wa = (float)((qa >> SH[c]) & 15) * sc8[c] - zs8[c];
        float wb = (float)((qb >> SH[c]) & 15) * sc8[c] - zs8[c];
        unsigned int pair = (unsigned int)f2bf(wa) | ((unsigned int)f2bf(wb) << 16);
        const int n = nloc + c;
        const int kk2 = (2 * kp) ^ (((n >> 3) & 3) << 3);
        *reinterpret_cast<unsigned int*>(&Bs[n * FLDST + kk2]) = pair;
      }
    }
    __syncthreads();
    if (t + 1 < 128) {
      const float* ap = aptr + (t + 1) * 32;
      #pragma unroll
      for (int i = 0; i < 4; ++i) apre[i] = *reinterpret_cast<const floatx4*>(ap + 4 * i);
      const int* qp = qptr + (size_t)(t + 1) * 32 * NPACK;
      qa = qp[0]; qb = qp[NPACK];
    }
    short8 af[4], bfv2[4];
    #pragma unroll
    for (int mf = 0; mf < 4; ++mf)
      af[mf] = *reinterpret_cast<const short8*>(&As[(arow0 + mf * 16) * FLDST + koff]);
    #pragma unroll
    for (int nf = 0; nf < 4; ++nf) {
      const int n = brow0 + nf * 16;
      const int kk = koff ^ (((n >> 3) & 3) << 3);
      bfv2[nf] = *reinterpret_cast<const short8*>(&Bs[n * FLDST + kk]);
    }
    #pragma unroll
    for (int mf = 0; mf < 4; ++mf)
      #pragma unroll
      for (int nf = 0; nf < 4; ++nf)
        acc[mf][nf] = __builtin_amdgcn_mfma_f32_16x16x32_bf16(af[mf], bfv2[nf], acc[mf][nf], 0, 0, 0);
    __syncthreads();
  }
  const int ocol = lane & 15, orow = (lane >> 4) << 2;
  #pragma unroll
  for (int nf = 0; nf < 4; ++nf) {
    const int gn = n0 + wn * 64 + nf * 16 + ocol;
    const float bv = BI[gn];
    #pragma unroll
    for (int mf = 0; mf < 4; ++mf) {
      const size_t gm = (size_t)(m0 + wm * 64 + mf * 16 + orow);
      #pragma unroll
      for (int j = 0; j < 4; ++j)
        OUT[(gm + j) * (size_t)N_TOT + gn] = acc[mf][nf][j] + bv;
    }
  }
}

extern "C" void kernel_launch(void* const* d_in, const int* in_sizes, int n_in,
                              void* d_out, int out_size, void* d_ws, size_t ws_size,
                              hipStream_t stream) {
  const float* x    = (const float*)d_in[0];
  const int*   qw   = (const int*)d_in[1];
  const int*   qz   = (const int*)d_in[2];
  const float* sc   = (const float*)d_in[3];
  const float* bias = (const float*)d_in[4];
  float* out = (float*)d_out;

  const size_t XH_BYTES = (size_t)M_TOT * K_TOT * 2;
  const size_t WT_BYTES = (size_t)N_TOT * K_TOT * 2;
  const size_t NEED = XH_BYTES + WT_BYTES;

  if (ws_size >= NEED) {
    __half* XH = (__half*)d_ws;
    __half* WT = (__half*)((char*)d_ws + XH_BYTES);
    k_cvt_x<<<2048, 256, 0, stream>>>(x, XH, M_TOT * K_TOT / 8);
    k_dequant<<<(N_TOT / 128) * (K_TOT / 128), 256, 0, stream>>>(qw, qz, sc, WT);
    k_gemm<<<(M_TOT / 256) * NBN2, 1024, 0, stream>>>(XH, WT, bias, out);
  } else {
    awq_fallback<<<(M_TOT / 128) * NBN, 256, 0, stream>>>(x, qw, qz, sc, bias, out);
  }
}